// Round 3
// baseline (814.987 us; speedup 1.0000x reference)
//
#include <hip/hip_runtime.h>

// CombPool2d: x (16,192,224,224) f32, w_avg/w_max (1,192,1,1) f32.
// out = w_avg^2 * avgpool2x2s2(x) + w_max^2 * maxpool2x2s2(x)  -> (16,192,112,112)
//
// Memory-bound: 616.6 MB read + 154.1 MB write. Read:write = 4:1, so this
// version optimizes the READ side: every global_load_dwordx4 is unit-stride
// dense across lanes (lane l -> 16 B at base + 16*l within each 28-lane row
// segment), vs the previous 2-strided pattern that touched 2x the cachelines
// per instruction. Each thread computes 4 outputs in one output row:
// pairs (2q, 2q+1) and (2q+56, 2q+57), stored as two dense float2 nt-stores.

typedef float f4 __attribute__((ext_vector_type(4)));
typedef float f2 __attribute__((ext_vector_type(2)));

#define IN_HW   (224 * 224)
#define OUT_HW  (112 * 112)
#define NCH     192

__global__ __launch_bounds__(256) void combpool2d_kernel(
    const float* __restrict__ x,
    const float* __restrict__ w_avg,
    const float* __restrict__ w_max,
    float* __restrict__ out,
    int n4)  // number of 4-output work items = out_size / 4
{
    int i = blockIdx.x * blockDim.x + threadIdx.x;
    if (i >= n4) return;

    // i -> (bc, oh, q) with q in [0,28): thread owns output cols
    // {2q, 2q+1} and {2q+56, 2q+57} of output row (bc, oh).
    int q  = i % 28;
    int t  = i / 28;
    int oh = t % 112;
    int bc = t / 112;
    int c  = bc % NCH;

    const float* row0 = x + (size_t)bc * IN_HW + (size_t)(2 * oh) * 224;
    const f4* r0 = (const f4*)row0;          // input row 2*oh   (56 float4s)
    const f4* r1 = (const f4*)(row0 + 224);  // input row 2*oh+1

    // All four loads: lane-dense unit stride (28-lane contiguous segments).
    f4 a0 = r0[q];        // cols 4q   .. 4q+3   (left half of row)
    f4 a1 = r0[q + 28];   // cols 4q+112 .. +115 (right half of row)
    f4 b0 = r1[q];
    f4 b1 = r1[q + 28];

    float ca = w_avg[c]; ca *= ca;
    float cm = w_max[c]; cm *= cm;

    f2 o0, o1;
    o0.x = ca * (0.25f * ((a0.x + a0.y) + (b0.x + b0.y)))
         + cm * fmaxf(fmaxf(a0.x, a0.y), fmaxf(b0.x, b0.y));
    o0.y = ca * (0.25f * ((a0.z + a0.w) + (b0.z + b0.w)))
         + cm * fmaxf(fmaxf(a0.z, a0.w), fmaxf(b0.z, b0.w));
    o1.x = ca * (0.25f * ((a1.x + a1.y) + (b1.x + b1.y)))
         + cm * fmaxf(fmaxf(a1.x, a1.y), fmaxf(b1.x, b1.y));
    o1.y = ca * (0.25f * ((a1.z + a1.w) + (b1.z + b1.w)))
         + cm * fmaxf(fmaxf(a1.z, a1.w), fmaxf(b1.z, b1.w));

    f2* orow = (f2*)(out + (size_t)bc * OUT_HW + (size_t)oh * 112);
    __builtin_nontemporal_store(o0, &orow[q]);        // out cols 2q, 2q+1
    __builtin_nontemporal_store(o1, &orow[q + 28]);   // out cols 2q+56, 2q+57
}

extern "C" void kernel_launch(void* const* d_in, const int* in_sizes, int n_in,
                              void* d_out, int out_size, void* d_ws, size_t ws_size,
                              hipStream_t stream) {
    const float* x     = (const float*)d_in[0];
    const float* w_avg = (const float*)d_in[1];
    const float* w_max = (const float*)d_in[2];
    float* out = (float*)d_out;

    int n4 = out_size / 4;                 // 9,633,792 work-items
    int block = 256;
    int grid = (n4 + block - 1) / block;   // full grid, one pass
    combpool2d_kernel<<<grid, block, 0, stream>>>(x, w_avg, w_max, out, n4);
}